// Round 2
// baseline (1292.880 us; speedup 1.0000x reference)
//
#include <hip/hip_runtime.h>
#include <stdint.h>

// ---------------------------------------------------------------------------
// ColorExtractor: per-image k-means (B=64, N=224*224, C=3, K=16, 10 iters).
// Threefry2x32 reproduced bit-exactly (jax_threefry_partitionable=True model,
// verified absmax 0.0 in R1). R2: parallelized kinit (was 409us @ 2.8% occ),
// branchless/vectorized kassign.
// ---------------------------------------------------------------------------

#define NB    64
#define NPIX  50176
#define NK    16
#define NCH   3
#define NITER 10
#define HBINS 2048
#define CANDCAP 2048
#define COLLCAP 128

typedef unsigned long long u64;

struct KeyPair { uint32_t a, b; };

__device__ __forceinline__ uint32_t rotl32(uint32_t v, uint32_t r) {
  return (v << r) | (v >> (32u - r));
}

__device__ __forceinline__ void tf_round(uint32_t& x0, uint32_t& x1, uint32_t r) {
  x0 += x1; x1 = rotl32(x1, r); x1 ^= x0;
}

// Threefry-2x32, 20 rounds, exactly as jax/_src/prng.py lowering.
__device__ __forceinline__ KeyPair threefry(uint32_t k0, uint32_t k1,
                                            uint32_t x0, uint32_t x1) {
  const uint32_t ks2 = k0 ^ k1 ^ 0x1BD11BDAu;
  x0 += k0; x1 += k1;
  tf_round(x0, x1, 13u); tf_round(x0, x1, 15u); tf_round(x0, x1, 26u); tf_round(x0, x1, 6u);
  x0 += k1;  x1 += ks2 + 1u;
  tf_round(x0, x1, 17u); tf_round(x0, x1, 29u); tf_round(x0, x1, 16u); tf_round(x0, x1, 24u);
  x0 += ks2; x1 += k0 + 2u;
  tf_round(x0, x1, 13u); tf_round(x0, x1, 15u); tf_round(x0, x1, 26u); tf_round(x0, x1, 6u);
  x0 += k0;  x1 += k1 + 3u;
  tf_round(x0, x1, 17u); tf_round(x0, x1, 29u); tf_round(x0, x1, 16u); tf_round(x0, x1, 24u);
  x0 += k1;  x1 += ks2 + 4u;
  tf_round(x0, x1, 13u); tf_round(x0, x1, 15u); tf_round(x0, x1, 26u); tf_round(x0, x1, 6u);
  x0 += ks2; x1 += k0 + 5u;
  KeyPair r; r.a = x0; r.b = x1; return r;
}

__device__ __forceinline__ uint32_t sortkey(KeyPair S, uint32_t i) {
  KeyPair r = threefry(S.a, S.b, 0u, i);   // counter = 64-bit iota (hi=0, lo=i)
  return r.a ^ r.b;                        // 32-bit path XOR-folds the block
}

__device__ __forceinline__ void derive_keys(int b, KeyPair& S1, KeyPair& S2) {
  KeyPair root; root.a = 0u; root.b = 42u;
  KeyPair kb = threefry(root.a, root.b, 0u, (uint32_t)b);   // foldlike split
  KeyPair K1 = threefry(kb.a, kb.b, 0u, 0u);                // key after round-1 split
  S1 = threefry(kb.a, kb.b, 0u, 1u);                        // round-1 subkey
  S2 = threefry(K1.a, K1.b, 0u, 1u);                        // round-2 subkey
}

#define T2VAL 27394240u  // ~2^32*320/NPIX: expect ~320 candidates/batch

// ---------------------------------------------------------------------------
// kinit split into 4 kernels for occupancy (R1 monolith: 409us @ 2.8% occ).
// perm[p] = s1(s2(p)): Phase A = 16 smallest (key2,i) -> target ranks;
// Phase B = stable-rank selection under key1 via 11-bit-prefix histogram.
// ---------------------------------------------------------------------------

// Pass A1: candidate filter under key2 + key1 prefix histogram. grid (32,NB).
__global__ __launch_bounds__(256) void kinit_a(uint32_t* __restrict__ ncand,
                                               u64* __restrict__ cand,
                                               uint32_t* __restrict__ hist) {
  const int b = (int)blockIdx.y;
  const int tid = (int)threadIdx.x;
  __shared__ uint32_t lh[HBINS];
  for (int i = tid; i < HBINS; i += 256) lh[i] = 0u;
  __syncthreads();
  KeyPair S1, S2;
  derive_keys(b, S1, S2);
  const int start = (int)blockIdx.x * (NPIX / 32);   // 1568 per block
  for (int i = start + tid; i < start + NPIX / 32; i += 256) {
    uint32_t k2 = sortkey(S2, (uint32_t)i);
    if (k2 < T2VAL) {
      uint32_t p = atomicAdd(&ncand[b], 1u);
      if (p < CANDCAP) cand[b * CANDCAP + p] = ((u64)k2 << 32) | (uint32_t)i;
    }
    uint32_t k1 = sortkey(S1, (uint32_t)i);
    atomicAdd(&lh[k1 >> 21], 1u);
  }
  __syncthreads();
  for (int i = tid; i < HBINS; i += 256)
    if (lh[i]) atomicAdd(&hist[b * HBINS + i], lh[i]);
}

// Pass A2/B1: rank candidates (top-16 under key2 -> Rtgt), locate each target
// rank's histogram bin + residual. grid NB.
__global__ __launch_bounds__(256) void kinit_b(const uint32_t* __restrict__ ncand,
                                               const u64* __restrict__ cand,
                                               const uint32_t* __restrict__ hist,
                                               uint32_t* __restrict__ binsel,
                                               uint32_t* __restrict__ rem) {
  const int b = (int)blockIdx.x;
  const int tid = (int)threadIdx.x;
  __shared__ u64 sc[CANDCAP];
  __shared__ uint32_t sh[HBINS];
  __shared__ uint32_t Rt[NK];
  const int M = ncand[b] < CANDCAP ? (int)ncand[b] : CANDCAP;
  for (int i = tid; i < M; i += 256) sc[i] = cand[b * CANDCAP + i];
  for (int i = tid; i < HBINS; i += 256) sh[i] = hist[b * HBINS + i];
  __syncthreads();
  // distinct (key,idx) pairs -> unique ranks; order-independent of atomics
  for (int j = tid; j < M; j += 256) {
    u64 me = sc[j];
    int r = 0;
    for (int t = 0; t < M; ++t) r += (sc[t] < me) ? 1 : 0;
    if (r < NK) Rt[r] = (uint32_t)(me & 0xffffffffu);
  }
  __syncthreads();
  if (tid < NK) {
    uint32_t R = Rt[tid], cum = 0u, bin = 0u;
    for (int i = 0; i < HBINS; ++i) {
      uint32_t h = sh[i];
      if (R < cum + h) { bin = (uint32_t)i; break; }
      cum += h;
    }
    binsel[b * NK + tid] = bin;
    rem[b * NK + tid] = R - cum;
  }
}

// Pass B2: collect key1 elements in each target's bin. grid (32,NB).
__global__ __launch_bounds__(256) void kinit_c(const uint32_t* __restrict__ binsel,
                                               uint32_t* __restrict__ ncoll,
                                               u64* __restrict__ coll) {
  const int b = (int)blockIdx.y;
  const int tid = (int)threadIdx.x;
  __shared__ uint32_t bs[NK];
  if (tid < NK) bs[tid] = binsel[b * NK + tid];
  __syncthreads();
  KeyPair S1, S2;
  derive_keys(b, S1, S2);
  const int start = (int)blockIdx.x * (NPIX / 32);
  for (int i = start + tid; i < start + NPIX / 32; i += 256) {
    uint32_t k1 = sortkey(S1, (uint32_t)i);
    uint32_t pb = k1 >> 21;
    #pragma unroll
    for (int t = 0; t < NK; ++t) {
      if (pb == bs[t]) {
        uint32_t p = atomicAdd(&ncoll[b * NK + t], 1u);
        if (p < COLLCAP) coll[(b * NK + t) * COLLCAP + p] = ((u64)k1 << 32) | (uint32_t)i;
      }
    }
  }
}

// Pass B3: stable select rem-th smallest (key1,idx), gather centroids, zero
// sums. grid NB, 64 threads.
__global__ __launch_bounds__(64) void kinit_d(const float* __restrict__ x,
                                              const uint32_t* __restrict__ rem,
                                              const uint32_t* __restrict__ ncoll,
                                              const u64* __restrict__ coll,
                                              float* __restrict__ cent,
                                              float* __restrict__ sums) {
  const int b = (int)blockIdx.x;
  const int t = (int)threadIdx.x;
  __shared__ int jsel[NK];
  if (t < NK) {
    const int m = ncoll[b * NK + t] < COLLCAP ? (int)ncoll[b * NK + t] : COLLCAP;
    const uint32_t r = rem[b * NK + t];
    const u64* c = &coll[(b * NK + t) * COLLCAP];
    u64 lo = 0ULL, cur = ~0ULL;
    bool first = true;
    for (uint32_t pass = 0; pass <= r; ++pass) {
      cur = ~0ULL;
      for (int i = 0; i < m; ++i) {
        u64 v = c[i];
        if ((first || v > lo) && v < cur) cur = v;
      }
      lo = cur; first = false;
    }
    jsel[t] = (int)(cur & 0xffffffffu);
  }
  __syncthreads();
  if (t < NK * NCH) {
    int k = t / NCH, c = t % NCH;
    cent[(b * NK + k) * NCH + c] = x[((size_t)b * NPIX + (size_t)jsel[k]) * NCH + c];
  }
  sums[b * NK * 4 + t] = 0.0f;
}

// ---------------------------------------------------------------------------
// Fallback monolithic kinit (R1-verified) if ws_size is too small.
// ---------------------------------------------------------------------------
__global__ __launch_bounds__(256) void kinit_mono(const float* __restrict__ x,
                                                  float* __restrict__ cent,
                                                  float* __restrict__ sums) {
  const int b = (int)blockIdx.x;
  const int tid = (int)threadIdx.x;
  __shared__ u64 cand[CANDCAP];
  __shared__ u64 coll[NK][COLLCAP];
  __shared__ uint32_t hist[HBINS];
  __shared__ uint32_t Rtgt[NK];
  __shared__ uint32_t binsel[NK];
  __shared__ uint32_t rem[NK];
  __shared__ int jsel[NK];
  __shared__ int ncand;
  __shared__ int ncoll[NK];

  KeyPair S1, S2;
  derive_keys(b, S1, S2);
  if (tid == 0) ncand = 0;
  if (tid < NK) ncoll[tid] = 0;
  for (int i = tid; i < HBINS; i += 256) hist[i] = 0u;
  __syncthreads();
  for (int i = tid; i < NPIX; i += 256) {
    uint32_t k2 = sortkey(S2, (uint32_t)i);
    if (k2 < T2VAL) {
      int p = atomicAdd(&ncand, 1);
      if (p < CANDCAP) cand[p] = ((u64)k2 << 32) | (uint32_t)i;
    }
    uint32_t k1 = sortkey(S1, (uint32_t)i);
    atomicAdd(&hist[k1 >> 21], 1u);
  }
  __syncthreads();
  const int M = ncand < CANDCAP ? ncand : CANDCAP;
  for (int j = tid; j < M; j += 256) {
    u64 me = cand[j];
    int rank = 0;
    for (int t = 0; t < M; ++t) rank += (cand[t] < me) ? 1 : 0;
    if (rank < NK) Rtgt[rank] = (uint32_t)(me & 0xffffffffu);
  }
  __syncthreads();
  if (tid < NK) {
    uint32_t R = Rtgt[tid], cum = 0u, bin = 0u;
    for (int i = 0; i < HBINS; ++i) {
      uint32_t h = hist[i];
      if (R < cum + h) { bin = (uint32_t)i; break; }
      cum += h;
    }
    binsel[tid] = bin;
    rem[tid] = R - cum;
  }
  __syncthreads();
  for (int i = tid; i < NPIX; i += 256) {
    uint32_t k1 = sortkey(S1, (uint32_t)i);
    uint32_t pb = k1 >> 21;
    #pragma unroll
    for (int t = 0; t < NK; ++t) {
      if (pb == binsel[t]) {
        int p = atomicAdd(&ncoll[t], 1);
        if (p < COLLCAP) coll[t][p] = ((u64)k1 << 32) | (uint32_t)i;
      }
    }
  }
  __syncthreads();
  if (tid < NK) {
    int m = ncoll[tid] < COLLCAP ? ncoll[tid] : COLLCAP;
    uint32_t r = rem[tid];
    u64 lo = 0ULL, cur = ~0ULL;
    bool first = true;
    for (uint32_t pass = 0; pass <= r; ++pass) {
      cur = ~0ULL;
      for (int t = 0; t < m; ++t) {
        u64 v = coll[tid][t];
        if ((first || v > lo) && v < cur) cur = v;
      }
      lo = cur; first = false;
    }
    jsel[tid] = (int)(cur & 0xffffffffu);
  }
  __syncthreads();
  if (tid < NK * NCH) {
    int k = tid / NCH, c = tid % NCH;
    cent[(b * NK + k) * NCH + c] = x[((size_t)b * NPIX + (size_t)jsel[k]) * NCH + c];
  }
  if (tid < NK * 4) sums[b * NK * 4 + tid] = 0.0f;
}

// ---------------------------------------------------------------------------
// kassign: branchless argmin + 4 pixels/thread via float4 + per-wave LDS acc.
// grid (49, NB): 49*256*4 = 50176 exactly. Arithmetic identical to R1
// (absmax 0.0): __f*_rn chain, strict <, ascending k. First-NaN argmin index
// is batch-uniform (x finite; d_k NaN iff centroid k has a NaN channel), so
// it's hoisted out of the pixel loop.
// ---------------------------------------------------------------------------
__global__ __launch_bounds__(256) void kassign(const float* __restrict__ x,
                                               const float* __restrict__ cent,
                                               float* __restrict__ sums) {
  const int b = (int)blockIdx.y;
  const int tid = (int)threadIdx.x;
  __shared__ float cs[NK * NCH];
  __shared__ float acc[4][NK * 4];
  __shared__ int knan_s;
  if (tid < NK * NCH) cs[tid] = cent[b * NK * NCH + tid];
  acc[tid >> 6][tid & 63] = 0.0f;
  __syncthreads();
  if (tid == 0) {
    int kn = -1;
    for (int k = 0; k < NK; ++k) {
      float a = cs[3 * k], bb = cs[3 * k + 1], cc = cs[3 * k + 2];
      if (a != a || bb != bb || cc != cc) { kn = k; break; }
    }
    knan_s = kn;
  }
  __syncthreads();

  float cr[NK * NCH];
  #pragma unroll
  for (int i = 0; i < NK * NCH; ++i) cr[i] = cs[i];

  const float* xb = x + (size_t)b * NPIX * NCH;
  const float4* p = (const float4*)(xb + (size_t)blockIdx.x * 3072);
  const float4 A = p[3 * tid], Bv = p[3 * tid + 1], Cv = p[3 * tid + 2];
  const float px[4][3] = {{A.x, A.y, A.z}, {A.w, Bv.x, Bv.y},
                          {Bv.z, Bv.w, Cv.x}, {Cv.y, Cv.z, Cv.w}};
  float* a0 = acc[tid >> 6];
  const int kn = knan_s;

  #pragma unroll
  for (int q = 0; q < 4; ++q) {
    const float v0 = px[q][0], v1 = px[q][1], v2 = px[q][2];
    int best = 0;
    float bd = 3.402823466e38f;
    #pragma unroll
    for (int k = 0; k < NK; ++k) {
      float d0 = __fsub_rn(v0, cr[3 * k + 0]);
      float d1 = __fsub_rn(v1, cr[3 * k + 1]);
      float d2 = __fsub_rn(v2, cr[3 * k + 2]);
      float d = __fadd_rn(__fadd_rn(__fmul_rn(d0, d0), __fmul_rn(d1, d1)),
                          __fmul_rn(d2, d2));
      bool c = d < bd;
      bd = c ? d : bd;
      best = c ? k : best;
    }
    if (kn >= 0) best = kn;   // np.argmin: first NaN wins (batch-uniform)
    atomicAdd(&a0[best * 4 + 0], v0);
    atomicAdd(&a0[best * 4 + 1], v1);
    atomicAdd(&a0[best * 4 + 2], v2);
    atomicAdd(&a0[best * 4 + 3], 1.0f);
  }
  __syncthreads();
  if (tid < NK * 4) {
    float v = acc[0][tid] + acc[1][tid] + acc[2][tid] + acc[3][tid];
    atomicAdd(&sums[b * NK * 4 + tid], v);
  }
}

// cent = sums/counts (0/0 -> NaN per reference), write d_out, re-zero sums.
__global__ __launch_bounds__(64) void kupdate(float* __restrict__ cent,
                                              float* __restrict__ sums,
                                              float* __restrict__ out) {
  const int b = (int)blockIdx.x;
  const int t = (int)threadIdx.x;
  float v = 0.0f;
  if (t < NK * NCH) {
    const int k = t / NCH, c = t % NCH;
    const float s = sums[b * NK * 4 + k * 4 + c];
    const float cnt = sums[b * NK * 4 + k * 4 + 3];
    v = s / cnt;
  }
  __syncthreads();
  if (t < NK * NCH) {
    cent[b * NK * NCH + t] = v;
    out[b * NK * NCH + t] = v;
  }
  sums[b * NK * 4 + t] = 0.0f;
}

extern "C" void kernel_launch(void* const* d_in, const int* in_sizes, int n_in,
                              void* d_out, int out_size, void* d_ws, size_t ws_size,
                              hipStream_t stream) {
  (void)in_sizes; (void)n_in; (void)out_size;
  const float* x = (const float*)d_in[0];
  float* out = (float*)d_out;
  char* ws = (char*)d_ws;

  // ws layout (bytes)
  float*    cent   = (float*)(ws + 0);              // 12288
  float*    sums   = (float*)(ws + 12288);          // 16384
  uint32_t* ncand  = (uint32_t*)(ws + 28672);       // 256    } zero
  uint32_t* ncoll  = (uint32_t*)(ws + 28928);       // 4096   } zone
  uint32_t* hist   = (uint32_t*)(ws + 33024);       // 524288 } 528640 B
  uint32_t* binsel = (uint32_t*)(ws + 557312);      // 4096
  uint32_t* rem    = (uint32_t*)(ws + 561408);      // 4096
  u64*      cand   = (u64*)(ws + 565504);           // 1048576
  u64*      coll   = (u64*)(ws + 1614080);          // 1048576
  const size_t REQ = 2662656;

  if (ws_size >= REQ) {
    hipMemsetAsync(ws + 28672, 0, 528640, stream);
    kinit_a<<<dim3(32, NB), 256, 0, stream>>>(ncand, cand, hist);
    kinit_b<<<NB, 256, 0, stream>>>(ncand, cand, hist, binsel, rem);
    kinit_c<<<dim3(32, NB), 256, 0, stream>>>(binsel, ncoll, coll);
    kinit_d<<<NB, 64, 0, stream>>>(x, rem, ncoll, coll, cent, sums);
  } else {
    kinit_mono<<<NB, 256, 0, stream>>>(x, cent, sums);
  }
  for (int it = 0; it < NITER; ++it) {
    kassign<<<dim3(49, NB), 256, 0, stream>>>(x, cent, sums);
    kupdate<<<NB, 64, 0, stream>>>(cent, sums, out);
  }
}